// Round 13
// baseline (55.788 us; speedup 1.0000x reference)
//
#include <hip/hip_runtime.h>
#include <hip/hip_bf16.h>

#define N_ 8192
#define D_ 256
#define NBLK 544  // sum_{bi} ceil((64-bi)/4) = 544 = 8*68 (XCD-bijective)

typedef float f32x4 __attribute__((ext_vector_type(4)));

// ws layout (doubles): [0..95] = 32 slots x {pos_cnt, pos_sim_sum, neg_sim_sum}
//                      [128..2175] = 512 lastrow wave-slots x {lp_s,lp_c,ln_s,ln_c}
// Xb (fp8 e4m3) at ws+32768, 2 MB. Row = 256 B = 4 windows of 64 B (K-step kt).
// Window w, chunk s: bytes[0:8] = k[w*64+s*8,+8), bytes[8:16] = k[w*64+32+s*8,+8).
// (R11-verified layout; staging/fragment addressing reused verbatim.)

// ---------------- prep: f32 -> fp8 interleaved rows + fp64 lastrow (R11) ----------
__global__ void prep_kernel(const float* __restrict__ X, const int* __restrict__ tg,
                            unsigned char* __restrict__ Xb, double* __restrict__ accd) {
  if (blockIdx.x < 512) {
    if (blockIdx.x == 0 && threadIdx.x < 96) accd[threadIdx.x] = 0.0;
    int t = blockIdx.x * 256 + threadIdx.x;
    int r = t >> 4, pc = t & 15;
    int w = pc >> 2, s = pc & 3;
    const float* row = X + (size_t)r * D_;
    int ka = w * 64 + s * 8;
    float4 a0 = *(const float4*)(row + ka);
    float4 a1 = *(const float4*)(row + ka + 4);
    float4 b0 = *(const float4*)(row + ka + 32);
    float4 b1 = *(const float4*)(row + ka + 36);
    int4 d;
    d.x = __builtin_amdgcn_cvt_pk_fp8_f32(a0.x, a0.y, 0, false);
    d.x = __builtin_amdgcn_cvt_pk_fp8_f32(a0.z, a0.w, d.x, true);
    d.y = __builtin_amdgcn_cvt_pk_fp8_f32(a1.x, a1.y, 0, false);
    d.y = __builtin_amdgcn_cvt_pk_fp8_f32(a1.z, a1.w, d.y, true);
    d.z = __builtin_amdgcn_cvt_pk_fp8_f32(b0.x, b0.y, 0, false);
    d.z = __builtin_amdgcn_cvt_pk_fp8_f32(b0.z, b0.w, d.z, true);
    d.w = __builtin_amdgcn_cvt_pk_fp8_f32(b1.x, b1.y, 0, false);
    d.w = __builtin_amdgcn_cvt_pk_fp8_f32(b1.z, b1.w, d.w, true);
    *(int4*)(Xb + (size_t)r * 256 + pc * 16) = d;
  } else {
    int lb = blockIdx.x - 512;  // 0..127
    int lane = threadIdx.x & 63, wv = threadIdx.x >> 6;
    const float4* xl = (const float4*)(X + (size_t)(N_ - 1) * D_);
    float4 a = xl[lane];
    int tlast = tg[N_ - 1];
    double lp = 0, lpc = 0, ln = 0, lnc = 0;
    for (int cc = 0; cc < 16; ++cc) {
      int j = lb * 64 + wv * 16 + cc;
      float4 bq = ((const float4*)(X + (size_t)j * D_))[lane];
      double s = (double)a.x * bq.x + (double)a.y * bq.y +
                 (double)a.z * bq.z + (double)a.w * bq.w;
#pragma unroll
      for (int off = 32; off; off >>= 1) s += __shfl_down(s, off);
      if (lane == 0) {
        float sf = (float)s;
        bool same = (tg[j] == tlast);
        if (same && sf < 1.0f) { lp += sf; lpc += 1.0; }
        if (!same) { ln += sf; lnc += 1.0; }
      }
    }
    if (lane == 0) {
      double* slot = accd + 128 + (size_t)(lb * 4 + wv) * 4;
      slot[0] = lp; slot[1] = lpc; slot[2] = ln; slot[3] = lnc;
    }
  }
}

// ---- 4-tile deep-pipeline fp8 GEMM: A-panel resident, B 3-deep stream, 16 steps ----
__global__ __launch_bounds__(256, 2) void simloss_kernel(
    const unsigned char* __restrict__ Xb, const int* __restrict__ tg,
    double* __restrict__ accd) {
  __shared__ __align__(16) char lds[32768 + 3 * 8192];  // A slabs kt*8192 | B at 32768+(s%3)*8192
  __shared__ float red[12];

  // ---- XCD swizzle + band/quad decode: cum(4a) = 66a - 2a^2 ----
  const int t0 = blockIdx.x;
  const int b = (t0 & 7) * (NBLK / 8) + (t0 >> 3);
#define FA(x) (66 * (x)-2 * (x) * (x))
  int a = (int)((66.0f - sqrtf(4356.0f - 8.0f * (float)b)) * 0.25f);
  if (a < 0) a = 0;
  if (a > 15) a = 15;
  while (a < 15 && FA(a + 1) <= b) ++a;
  while (a > 0 && FA(a) > b) --a;
  int off = b - FA(a);
  const int nbb = 16 - a;  // blocks per band in group a
  int r = 0;
  while (off >= nbb) { off -= nbb; ++r; }
  const int bi = 4 * a + r;     // row band: rows [bi*128, +128)
  const int j0 = bi + 4 * off;  // first of 4 column tiles
#undef FA

  const int tid = threadIdx.x;
  const int lane = tid & 63, wv = tid >> 6;
  const int wr = wv >> 1, wc = wv & 1;
  const int rowA0 = bi * 128;

  int bj[4];
  float wt[4];
#pragma unroll
  for (int tt = 0; tt < 4; ++tt) {
    int j = j0 + tt;
    wt[tt] = (j > 63) ? 0.0f : (j == bi ? 1.0f : 2.0f);  // pad tiles weight 0
    bj[tt] = (j > 63) ? 63 : j;
  }

  // ---- prologue tg loads (oldest VMEM; retire under step-0 vmcnt wait) ----
  const int fr = lane & 15, slv = lane >> 4;
  const int cRow = slv * 4, cCol = fr;
  int ti[4][4], tjq[4][4];
#pragma unroll
  for (int m = 0; m < 4; ++m) {
    int4 v = *(const int4*)(tg + rowA0 + wr * 64 + m * 16 + cRow);
    ti[m][0] = v.x; ti[m][1] = v.y; ti[m][2] = v.z; ti[m][3] = v.w;
  }
#pragma unroll
  for (int tt = 0; tt < 4; ++tt)
#pragma unroll
    for (int n = 0; n < 4; ++n) tjq[tt][n] = tg[bj[tt] * 128 + wc * 64 + n * 16 + cCol];

  // ---- staging constants (R11-verified) ----
  const int srow = tid >> 2;
  const int sw = (tid & 3) ^ ((srow >> 1) & 3);
  const unsigned char* bA = Xb + (size_t)(rowA0 + srow) * 256 + sw * 16;
  const unsigned char* pB[4];
#pragma unroll
  for (int tt = 0; tt < 4; ++tt)
    pB[tt] = Xb + (size_t)(bj[tt] * 128 + srow) * 256 + sw * 16;

#define GLDS(g, l) \
  __builtin_amdgcn_global_load_lds((const __attribute__((address_space(1))) void*)(g), \
                                   (__attribute__((address_space(3))) void*)(l), 16, 0, 0)
#define STAGE_B(s)                                              \
  do {                                                          \
    char* d = lds + 32768 + ((s) % 3) * 8192;                   \
    const unsigned char* src = pB[(s) >> 2] + ((s)&3) * 64;     \
    GLDS(src, d + tid * 16);                                    \
    GLDS(src + 16384, d + 4096 + tid * 16);                     \
  } while (0)

  __builtin_amdgcn_sched_barrier(0);  // keep tg loads oldest in VMEM queue
  // stage A panel once: 4 slabs (one per K-step), 8 ops
#pragma unroll
  for (int kt = 0; kt < 4; ++kt) {
    GLDS(bA + kt * 64, lds + kt * 8192 + tid * 16);
    GLDS(bA + 16384 + kt * 64, lds + kt * 8192 + 4096 + tid * 16);
  }
  STAGE_B(0);
  STAGE_B(1);  // in flight: tg(oldest) + A(8) + B0(2) + B1(2)

  // ---- fragment-read constants (R11-verified swizzle; 0 conflicts) ----
  const int rswz = slv ^ ((fr >> 1) & 3);
  const int aoff = (wr * 64 + fr) * 64 + rswz * 16;
  const int boff = (wc * 64 + fr) * 64 + rswz * 16;

  f32x4 acc[4][4] = {};
  float pcT = 0.f, psT = 0.f, nsT = 0.f;
  union U { int4 v; long l[2]; };

#pragma unroll
  for (int s = 0; s < 16; ++s) {
    asm volatile("s_waitcnt lgkmcnt(0)" ::: "memory");  // my prev-step ds_reads retired
    __builtin_amdgcn_sched_barrier(0);                  // rule #18 fence
    if (s < 15)
      asm volatile("s_waitcnt vmcnt(2)" ::: "memory");  // only next step's B in flight
    else
      asm volatile("s_waitcnt vmcnt(0)" ::: "memory");
    __builtin_amdgcn_s_barrier();  // step-s data visible to all; prev reads done
    if (s + 2 < 16) STAGE_B(s + 2);

    const int kt = s & 3, tt = s >> 2;
    const char* Ab = lds + kt * 8192;
    const char* Bb = lds + 32768 + (s % 3) * 8192;
    U a4[4], b4[4];
#pragma unroll
    for (int m = 0; m < 4; ++m) a4[m].v = *(const int4*)(Ab + aoff + m * 1024);
#pragma unroll
    for (int n = 0; n < 4; ++n) b4[n].v = *(const int4*)(Bb + boff + n * 1024);
#pragma unroll
    for (int m = 0; m < 4; ++m)
#pragma unroll
      for (int n = 0; n < 4; ++n) {
        acc[m][n] = __builtin_amdgcn_mfma_f32_16x16x32_fp8_fp8(a4[m].l[0], b4[n].l[0],
                                                               acc[m][n], 0, 0, 0);
        acc[m][n] = __builtin_amdgcn_mfma_f32_16x16x32_fp8_fp8(a4[m].l[1], b4[n].l[1],
                                                               acc[m][n], 0, 0, 0);
      }

    if (kt == 3) {  // tile epilogue: pure VALU/registers, no VMEM, no barrier
      float pc = 0.f, ps = 0.f, ns = 0.f;
#pragma unroll
      for (int m = 0; m < 4; ++m)
#pragma unroll
        for (int n = 0; n < 4; ++n)
#pragma unroll
          for (int rg = 0; rg < 4; ++rg) {
            float sv = acc[m][n][rg];
            bool same = (ti[m][rg] == tjq[tt][n]);
            if (same & (sv < 0.9f)) { pc += 1.0f; ps += sv; }
            if ((!same) & (sv > 0.5f)) { ns += sv; }
          }
      pcT += wt[tt] * pc;
      psT += wt[tt] * ps;
      nsT += wt[tt] * ns;
#pragma unroll
      for (int m = 0; m < 4; ++m)
#pragma unroll
        for (int n = 0; n < 4; ++n) acc[m][n] = f32x4{0.f, 0.f, 0.f, 0.f};
    }
  }
#undef STAGE_B
#undef GLDS

  // ---- block reduction + per-slot atomics ----
#pragma unroll
  for (int off2 = 32; off2 > 0; off2 >>= 1) {
    pcT += __shfl_down(pcT, off2);
    psT += __shfl_down(psT, off2);
    nsT += __shfl_down(nsT, off2);
  }
  if (lane == 0) { red[0 + wv] = pcT; red[4 + wv] = psT; red[8 + wv] = nsT; }
  __syncthreads();
  if (tid == 0) {
    double* slot = accd + (blockIdx.x & 31) * 3;
    atomicAdd(&slot[0], (double)(red[0] + red[1] + red[2] + red[3]));
    atomicAdd(&slot[1], (double)(red[4] + red[5] + red[6] + red[7]));
    atomicAdd(&slot[2], (double)(red[8] + red[9] + red[10] + red[11]));
  }
}

// ---------------- finalize (single wave) ----------------
__global__ void finalize_kernel(const double* __restrict__ accd, float* __restrict__ out) {
  int l = threadIdx.x;  // 64 threads
  double lp = 0, lpc = 0, ln = 0, lnc = 0;
  for (int q = l; q < 512; q += 64) {
    const double* s = accd + 128 + (size_t)q * 4;
    lp += s[0]; lpc += s[1]; ln += s[2]; lnc += s[3];
  }
  double pc = 0, ps = 0, ns = 0;
  if (l < 32) { pc = accd[l * 3]; ps = accd[l * 3 + 1]; ns = accd[l * 3 + 2]; }
#pragma unroll
  for (int off = 32; off > 0; off >>= 1) {
    lp += __shfl_down(lp, off);  lpc += __shfl_down(lpc, off);
    ln += __shfl_down(ln, off);  lnc += __shfl_down(lnc, off);
    pc += __shfl_down(pc, off);  ps += __shfl_down(ps, off);
    ns += __shfl_down(ns, off);
  }
  if (l == 0) {
    out[0] = (float)((pc - ps + ns) / (double)N_);
    out[1] = 0.0f;  // prec: reference never increments c
    out[2] = (float)(lp / fmax(lpc, 1.0));
    out[3] = (float)(ln / fmax(lnc, 1.0));
  }
}

extern "C" void kernel_launch(void* const* d_in, const int* in_sizes, int n_in,
                              void* d_out, int out_size, void* d_ws, size_t ws_size,
                              hipStream_t stream) {
  const float* X = (const float*)d_in[0];
  const int* tg = (const int*)d_in[1];
  float* out = (float*)d_out;
  double* accd = (double*)d_ws;
  unsigned char* Xb = (unsigned char*)d_ws + 32768;

  prep_kernel<<<512 + 128, 256, 0, stream>>>(X, tg, Xb, accd);
  simloss_kernel<<<NBLK, 256, 0, stream>>>(Xb, tg, accd);
  finalize_kernel<<<1, 64, 0, stream>>>(accd, out);
}